// Round 8
// baseline (22.552 us; speedup 1.0000x reference)
//
#include <hip/hip_runtime.h>
#include <math.h>

#define BB 32
#define HH 256
#define NN 8192
#define NC 16                 // chunks over N
#define PHALF 2               // plane halves
#define CHUNK (NN / NC)       // 512 points per chunk
#define PPB (HH / PHALF)      // 128 planes per block
#define P 4                   // planes per thread
#define SUB (CHUNK / 8)       // 64 points per sub-range

// ws layout (floats):
//   planes : BB*HH*4 = 32768 floats at 0      (float4 per plane)
//   loss   : BB*HH   =  8192 floats at 32768
//   partial: BB*PHALF*NC*PPB = 131072 floats at 40960
#define WS_LOSS_F ((size_t)BB * HH * 4)
#define WS_PART_F (WS_LOSS_F + (size_t)BB * HH)

// Block = (128 planes, 512-pt chunk); 1024 blocks = 4 blocks/CU = 4 waves/SIMD
// for latency hiding + block-tail smoothing. Waves 0-1 fit this block's 128
// planes (scattered L2-hit gather) WHILE waves 2-3 stage the chunk via
// global_load_lds. No cross-block sync, no fences (rounds 2/4 lesson).
__global__ __launch_bounds__(256) void score_kernel(
    const float* __restrict__ pts, const float* __restrict__ target,
    const int* __restrict__ sidx, float* __restrict__ ws,
    float* __restrict__ partial) {
  const int bx = blockIdx.x;            // [0,32)
  const int ph = bx >> 4, chunk = bx & 15;
  const int b = blockIdx.y;
  const int h = threadIdx.x;

  __shared__ float4 smp[CHUNK * 3 / 4];   // 6 KB chunk points (384 float4)
  __shared__ float4 plane_lds[PPB];       // 2 KB planes (unscaled)
  __shared__ float scorepad[PPB * 9];     // 4.5 KB padded reduce pad

  if (h >= 128) {
    // ---- waves 2-3: async stage of 384 float4 (lane-contiguous dests) ----
    const float4* src4 =
        (const float4*)(pts + ((long)b * NN + (long)chunk * CHUNK) * 3);
    const int l = h - 128;
#pragma unroll
    for (int i = 0; i < 3; ++i) {
      __builtin_amdgcn_global_load_lds(src4 + l + 128 * i, &smp[l + 128 * i],
                                       16, 0, 0);
    }
  } else {
    // ---- waves 0-1: fit plane ph*128+h of batch b ----
    long ibase = ((long)b * HH + ph * PPB + h) * 3;
    int i0 = sidx[ibase], i1 = sidx[ibase + 1], i2 = sidx[ibase + 2];
    const float* pb = pts + (long)b * NN * 3;
    float p0x = pb[3 * i0], p0y = pb[3 * i0 + 1], p0z = pb[3 * i0 + 2];
    float p1x = pb[3 * i1], p1y = pb[3 * i1 + 1], p1z = pb[3 * i1 + 2];
    float p2x = pb[3 * i2], p2y = pb[3 * i2 + 1], p2z = pb[3 * i2 + 2];
    float v1x = p1x - p0x, v1y = p1y - p0y, v1z = p1z - p0z;
    float v2x = p2x - p0x, v2y = p2y - p0y, v2z = p2z - p0z;
    // explicit non-FMA cross product: degenerate triples must give EXACT
    // zero to match numpy's all_zero replacement path.
    float nx = __fsub_rn(__fmul_rn(v1y, v2z), __fmul_rn(v1z, v2y));
    float ny = __fsub_rn(__fmul_rn(v1z, v2x), __fmul_rn(v1x, v2z));
    float nz = __fsub_rn(__fmul_rn(v1x, v2y), __fmul_rn(v1y, v2x));
    float d = -(__fmul_rn(nx, p0x) + __fmul_rn(ny, p0y) + __fmul_rn(nz, p0z));
    if (nx == 0.0f && ny == 0.0f && nz == 0.0f && d == 0.0f) {
      nx = 1.0f; ny = 1.0f; nz = 1.0f; d = 1.0f;
    }
    // rsq + mul normalize (~1e-7 rel err; threshold is 0.17 — safe)
    float inv = __builtin_amdgcn_rsqf(nx * nx + ny * ny + nz * nz);
    nx *= inv; ny *= inv; nz *= inv; d *= inv;
    plane_lds[h] = make_float4(nx, ny, nz, d);

    if (chunk == 0) {  // one block per (batch, plane-half) persists
      ((float4*)ws)[b * HH + ph * PPB + h] = make_float4(nx, ny, nz, d);
      float tx = target[b * 3], ty = target[b * 3 + 1], tz = target[b * 3 + 2];
      float lm = (nx - tx) * (nx - tx) + (ny - ty) * (ny - ty) +
                 (nz - tz) * (nz - tz);
      float lp = (nx + tx) * (nx + tx) + (ny + ty) * (ny + ty) +
                 (nz + tz) * (nz + tz);
      ws[WS_LOSS_F + b * HH + ph * PPB + h] = fminf(lm, lp);
    }
  }
  __syncthreads();  // planes in LDS + points staged

  // ---- load P=4 planes, pre-scaled by sqrt(50*log2 e) ----
  const float SC = 8.4932180028801371f;
  const int pid = h & 31;
  const int s = h >> 5;  // point sub-range [0,8)
  float4 pls[P];
#pragma unroll
  for (int k = 0; k < P; ++k) {
    float4 q = plane_lds[pid + (k << 5)];
    pls[k] = make_float4(q.x * SC, q.y * SC, q.z * SC, q.w * SC);
  }

  // ---- score: 64 points x 4 planes per thread (2-addr broadcast reads) ----
  float acc[P];
#pragma unroll
  for (int k = 0; k < P; ++k) acc[k] = 0.f;
  const int sbase = s * (SUB * 3 / 4);  // 48 float4 per sub-range
#pragma unroll 4
  for (int g = 0; g < SUB / 4; ++g) {  // 4 points per iter
    float4 v0 = smp[sbase + 3 * g + 0];
    float4 v1 = smp[sbase + 3 * g + 1];
    float4 v2 = smp[sbase + 3 * g + 2];
#pragma unroll
    for (int k = 0; k < P; ++k) {
      float4 q = pls[k];
      float t0 = fmaf(q.x, v0.x, fmaf(q.y, v0.y, fmaf(q.z, v0.z, q.w)));
      float t1 = fmaf(q.x, v0.w, fmaf(q.y, v1.x, fmaf(q.z, v1.y, q.w)));
      float t2 = fmaf(q.x, v1.z, fmaf(q.y, v1.w, fmaf(q.z, v2.x, q.w)));
      float t3 = fmaf(q.x, v2.y, fmaf(q.y, v2.z, fmaf(q.z, v2.w, q.w)));
      float e0 = __builtin_amdgcn_exp2f(-(t0 * t0));
      float e1 = __builtin_amdgcn_exp2f(-(t1 * t1));
      float e2 = __builtin_amdgcn_exp2f(-(t2 * t2));
      float e3 = __builtin_amdgcn_exp2f(-(t3 * t3));
      acc[k] += (e0 + e1) + (e2 + e3);
    }
  }

  // ---- in-block reduce across sub-ranges (stride-9 pad, conflict-free) ----
#pragma unroll
  for (int k = 0; k < P; ++k) scorepad[(pid + (k << 5)) * 9 + s] = acc[k];
  __syncthreads();
  if (h < PPB) {
    float rowsum = 0.f;
#pragma unroll
    for (int j = 0; j < 8; ++j) rowsum += scorepad[h * 9 + j];
    partial[(((long)b * PHALF + ph) * NC + chunk) * PPB + h] = rowsum;
  }
}

__global__ __launch_bounds__(HH) void finalize_kernel(
    const float* __restrict__ ws, float* __restrict__ out) {
  int b = blockIdx.x, h = threadIdx.x;  // h = global plane id
  const float* lossArr = ws + WS_LOSS_F;
  const float* partial = ws + WS_PART_F;
  const int ph = h >> 7, idx = h & 127;
  float s = 0.f;
#pragma unroll
  for (int c = 0; c < NC; ++c)
    s += partial[(((long)b * PHALF + ph) * NC + c) * PPB + idx];
  float l = lossArr[b * HH + h];

  __shared__ float redv[4];
  __shared__ int redi[4];
  __shared__ float sw[4], swl[4];

  // ---- wave-level argmax via shuffles (first-index tie-break) ----
  float v = s; int vidx = h;
#pragma unroll
  for (int o = 32; o > 0; o >>= 1) {
    float ov = __shfl_xor(v, o);
    int oi = __shfl_xor(vidx, o);
    if (ov > v || (ov == v && oi < vidx)) { v = ov; vidx = oi; }
  }
  const int wid = h >> 6;
  if ((h & 63) == 0) { redv[wid] = v; redi[wid] = vidx; }
  __syncthreads();
  float m = redv[0]; int mi = redi[0];
#pragma unroll
  for (int w = 1; w < 4; ++w) {
    float ov = redv[w]; int oi = redi[w];
    if (ov > m || (ov == m && oi < mi)) { m = ov; mi = oi; }
  }

  // ---- softmax sums via shuffles ----
  const float HL = 0.72134752044448170f;  // 0.5 * log2(e)
  float wv = __builtin_amdgcn_exp2f(HL * (s - m));
  float wl = wv * l;
#pragma unroll
  for (int o = 32; o > 0; o >>= 1) {
    wv += __shfl_xor(wv, o);
    wl += __shfl_xor(wl, o);
  }
  if ((h & 63) == 0) { sw[wid] = wv; swl[wid] = wl; }
  __syncthreads();
  if (h == 0) {
    float S1 = (sw[0] + sw[1]) + (sw[2] + sw[3]);
    float S2 = (swl[0] + swl[1]) + (swl[2] + swl[3]);
    out[b] = S2 / S1;                       // exp_loss
    out[BB + b] = lossArr[b * HH + mi];     // top_loss
    float4 p = ((const float4*)ws)[b * HH + mi];
    out[2 * BB + 3 * b + 0] = p.x;          // pred
    out[2 * BB + 3 * b + 1] = p.y;
    out[2 * BB + 3 * b + 2] = p.z;
  }
}

extern "C" void kernel_launch(void* const* d_in, const int* in_sizes, int n_in,
                              void* d_out, int out_size, void* d_ws, size_t ws_size,
                              hipStream_t stream) {
  const float* pts = (const float*)d_in[0];
  const float* target = (const float*)d_in[1];
  const int* sidx = (const int*)d_in[2];
  float* out = (float*)d_out;
  float* ws = (float*)d_ws;
  float* partial = ws + WS_PART_F;

  score_kernel<<<dim3(PHALF * NC, BB), 256, 0, stream>>>(pts, target, sidx, ws,
                                                         partial);
  finalize_kernel<<<BB, HH, 0, stream>>>(ws, out);
}